// Round 3
// baseline (30042.209 us; speedup 1.0000x reference)
//
#include <hip/hip_runtime.h>

#define BB   32
#define DD   512
#define RR   4
#define MM   64
#define VV   10000
#define TT   64
#define IFX  3607
#define NNIN 2560
#define EPSF 1e-6f

typedef unsigned short u16;

// bf16 helpers for INTERNAL scratch only (full/y buffers)
__device__ __forceinline__ float bf(u16 u){ return __uint_as_float(((unsigned)u)<<16); }
__device__ __forceinline__ float4 b4f(ushort4 u){
  float4 f; f.x = bf(u.x); f.y = bf(u.y); f.z = bf(u.z); f.w = bf(u.w); return f;
}
__device__ __forceinline__ u16 f2b(float f){
  unsigned u = __float_as_uint(f);
  u += 0x7fffu + ((u>>16)&1u);
  return (u16)(u>>16);
}
__device__ __forceinline__ float sigmf(float x){ return 1.f/(1.f+__expf(-x)); }
__device__ __forceinline__ float softplusf(float x){ return x > 20.f ? x : log1pf(__expf(x)); }
__device__ __forceinline__ float wredSum(float v){
  #pragma unroll
  for (int s=1;s<64;s<<=1) v += __shfl_xor(v,s,64);
  return v;
}
__device__ __forceinline__ float wredMax(float v){
  #pragma unroll
  for (int s=1;s<64;s<<=1) v = fmaxf(v, __shfl_xor(v,s,64));
  return v;
}

// Fused gates GEMM + LSTM cell update.
// Block: 8 d-values (32 gate-cols) x 32 batches. grid=64, 256 thr.
__global__ __launch_bounds__(256) void k_lstm(
    const float* __restrict__ Wx, int wx_stride,
    const float* __restrict__ Wh,
    const float* __restrict__ bx, const float* __restrict__ bh,
    const float* __restrict__ emb, const int* __restrict__ seq, int t,
    const float* __restrict__ xf,
    const float* __restrict__ hprev, float* __restrict__ hcur,
    float* __restrict__ cst, float* __restrict__ outc, u16* __restrict__ full)
{
  __shared__ __align__(16) float As[32][136];
  __shared__ float gs[32*33];
  __shared__ int idxs[32];
  const int tid = threadIdx.x;
  const int c = tid & 31;
  const int gate = c >> 3, dl = c & 7;
  const int dblk = blockIdx.x * 8;
  const int gcol = gate*512 + dblk + dl;
  const int b0 = (tid >> 5) * 4;
  float acc0=0.f, acc1=0.f, acc2=0.f, acc3=0.f;
  if (emb != nullptr && tid < 32) idxs[tid] = seq[tid*64 + t];
  __syncthreads();
  for (int chunk = 0; chunk < 8; ++chunk) {
    const int k0 = chunk * 128;
    const bool xp = (chunk < 4);
    for (int i = tid; i < 32*128; i += 256) {
      const int bb2 = i >> 7, kk = i & 127;
      float v;
      if (xp) v = (emb != nullptr) ? emb[(size_t)idxs[bb2]*512 + k0 + kk]
                                   : xf[bb2*512 + k0 + kk];
      else    v = hprev[bb2*512 + (k0-512) + kk];
      As[bb2][kk] = v;
    }
    __syncthreads();
    const float* Wr = xp ? (Wx + (size_t)gcol*wx_stride + k0)
                         : (Wh + (size_t)gcol*512 + (k0-512));
    #pragma unroll 8
    for (int kk = 0; kk < 128; kk += 4) {
      const float4 w4 = *(const float4*)(Wr + kk);
      const float4 a0 = *(const float4*)&As[b0+0][kk];
      const float4 a1 = *(const float4*)&As[b0+1][kk];
      const float4 a2 = *(const float4*)&As[b0+2][kk];
      const float4 a3 = *(const float4*)&As[b0+3][kk];
      acc0 = fmaf(a0.x,w4.x,fmaf(a0.y,w4.y,fmaf(a0.z,w4.z,fmaf(a0.w,w4.w,acc0))));
      acc1 = fmaf(a1.x,w4.x,fmaf(a1.y,w4.y,fmaf(a1.z,w4.z,fmaf(a1.w,w4.w,acc1))));
      acc2 = fmaf(a2.x,w4.x,fmaf(a2.y,w4.y,fmaf(a2.z,w4.z,fmaf(a2.w,w4.w,acc2))));
      acc3 = fmaf(a3.x,w4.x,fmaf(a3.y,w4.y,fmaf(a3.z,w4.z,fmaf(a3.w,w4.w,acc3))));
    }
    __syncthreads();
  }
  const float bias = bx[gcol] + bh[gcol];
  gs[c*33 + b0+0] = acc0 + bias;
  gs[c*33 + b0+1] = acc1 + bias;
  gs[c*33 + b0+2] = acc2 + bias;
  gs[c*33 + b0+3] = acc3 + bias;
  __syncthreads();
  {
    const int b2 = tid & 31, dl2 = tid >> 5;
    const float gi = gs[(0*8+dl2)*33 + b2];
    const float gf = gs[(1*8+dl2)*33 + b2];
    const float gg = gs[(2*8+dl2)*33 + b2];
    const float go = gs[(3*8+dl2)*33 + b2];
    const int d = dblk + dl2;
    const int cid = b2*512 + d;
    const float cv = sigmf(gf)*cst[cid] + sigmf(gi)*tanhf(gg);
    const float hv = sigmf(go)*tanhf(cv);
    cst[cid] = cv;
    hcur[cid] = hv;
    if (outc != nullptr) {
      const float oc = fminf(fmaxf(hv,-20.f),20.f);
      outc[cid] = oc;
      if (full != nullptr) full[((size_t)t*32 + b2)*2560 + d] = f2b(oc);
    }
  }
}

// xi = out @ Wi.T + bi  (B x IFX). grid=113 (32 cols each), 256 thr.
__global__ __launch_bounds__(256) void k_xi(
    const float* __restrict__ outc,
    const float* __restrict__ Wi, const float* __restrict__ bi,
    float* __restrict__ xi)
{
  __shared__ __align__(16) float As[32][136];
  const int tid = threadIdx.x;
  const int c = tid & 31;
  const int col = blockIdx.x*32 + c;
  const int colc = col < IFX ? col : IFX-1;
  const int b0 = (tid>>5)*4;
  float acc0=0.f,acc1=0.f,acc2=0.f,acc3=0.f;
  for (int chunk = 0; chunk < 4; ++chunk) {
    const int k0 = chunk*128;
    for (int i = tid; i < 32*128; i += 256) {
      const int bb2 = i>>7, kk = i&127;
      As[bb2][kk] = outc[bb2*512 + k0 + kk];
    }
    __syncthreads();
    const float* Wr = Wi + (size_t)colc*512 + k0;
    #pragma unroll 8
    for (int kk = 0; kk < 128; kk += 4) {
      const float4 w4 = *(const float4*)(Wr + kk);
      const float4 a0 = *(const float4*)&As[b0+0][kk];
      const float4 a1 = *(const float4*)&As[b0+1][kk];
      const float4 a2 = *(const float4*)&As[b0+2][kk];
      const float4 a3 = *(const float4*)&As[b0+3][kk];
      acc0 = fmaf(a0.x,w4.x,fmaf(a0.y,w4.y,fmaf(a0.z,w4.z,fmaf(a0.w,w4.w,acc0))));
      acc1 = fmaf(a1.x,w4.x,fmaf(a1.y,w4.y,fmaf(a1.z,w4.z,fmaf(a1.w,w4.w,acc1))));
      acc2 = fmaf(a2.x,w4.x,fmaf(a2.y,w4.y,fmaf(a2.z,w4.z,fmaf(a2.w,w4.w,acc2))));
      acc3 = fmaf(a3.x,w4.x,fmaf(a3.y,w4.y,fmaf(a3.z,w4.z,fmaf(a3.w,w4.w,acc3))));
    }
    __syncthreads();
  }
  if (col < IFX) {
    const float bias = bi[col];
    xi[(size_t)(b0+0)*IFX + col] = acc0 + bias;
    xi[(size_t)(b0+1)*IFX + col] = acc1 + bias;
    xi[(size_t)(b0+2)*IFX + col] = acc2 + bias;
    xi[(size_t)(b0+3)*IFX + col] = acc3 + bias;
  }
}

// DNC memory step, one block per batch. 256 thr. Norms recomputed from mem.
__global__ __launch_bounds__(256) void k_mem(
    const float* __restrict__ xi,
    float* __restrict__ mem,
    float* __restrict__ link, float* __restrict__ prec,
    float* __restrict__ rwg, float* __restrict__ wwg, float* __restrict__ usg,
    u16* __restrict__ full, int t)
{
  const int b = blockIdx.x, tid = threadIdx.x;
  const float* xb = xi + (size_t)b*IFX;
  __shared__ __align__(16) float rk_s[4][512];
  __shared__ __align__(16) float wk_s[512];
  __shared__ __align__(16) float er_s[512];
  __shared__ __align__(16) float wv_s[512];
  __shared__ float rwp_s[4][64];
  __shared__ float prec_s[64], usage_s[64], wcw_s[64], u_s[64], ww_s[64];
  __shared__ float sorted_s[64], excl_s[64];
  __shared__ int rank_s[64];
  __shared__ float cw_s[4][64], rwn_s[4][64];
  __shared__ float link_s[64][65];
  __shared__ float mn_s[64];
  __shared__ float sc[40];
  // sc: [0..3] rs, [4] ws, [5..8] fg, [9] ag, [10] wg, [11..22] modes, [23] |wk|, [24..27] |rk_r|, [28] sum(ww)

  // ---- phase 0: parse xi (activations), load prev state ----
  for (int i = tid; i < 2048; i += 256) rk_s[i>>9][i&511] = tanhf(xb[i]);
  for (int i = tid; i < 512; i += 256) {
    wk_s[i] = tanhf(xb[2052+i]);
    er_s[i] = sigmf(xb[2565+i]);
    wv_s[i] = tanhf(xb[3077+i]);
  }
  rwp_s[tid>>6][tid&63] = rwg[b*256 + tid];
  if (tid < 64) { prec_s[tid] = prec[b*64+tid]; usage_s[tid] = usg[b*64+tid]; }
  if (tid == 0) {
    for (int r=0;r<4;r++) sc[r] = softplusf(xb[2048+r]);
    sc[4] = softplusf(xb[2564]);
    for (int r=0;r<4;r++) sc[5+r] = sigmf(xb[3589+r]);
    sc[9]  = sigmf(xb[3593]);
    sc[10] = sigmf(xb[3594]);
    for (int r=0;r<4;r++) {
      const float a0=xb[3595+3*r], a1=xb[3596+3*r], a2=xb[3597+3*r];
      const float mx=fmaxf(a0,fmaxf(a1,a2));
      const float e0=__expf(a0-mx), e1=__expf(a1-mx), e2=__expf(a2-mx);
      const float s=e0+e1+e2;
      sc[11+3*r]=e0/s; sc[12+3*r]=e1/s; sc[13+3*r]=e2/s;
    }
  }
  __syncthreads();
  // ---- norms of rk (wave r) and wk (wave 0) ----
  {
    const int wid = tid>>6, ln = tid&63;
    float p = 0.f;
    for (int i = ln; i < 512; i += 64) { const float v = rk_s[wid][i]; p = fmaf(v,v,p); }
    p = wredSum(p);
    if (ln == 0) sc[24+wid] = sqrtf(p);
    if (wid == 0) {
      float q2 = 0.f;
      for (int i = ln; i < 512; i += 64) { const float v = wk_s[i]; q2 = fmaf(v,v,q2); }
      q2 = wredSum(q2);
      if (ln == 0) sc[23] = sqrtf(q2);
    }
  }
  __syncthreads();
  // ---- phase 2: wcw raw cosine (old mem, fresh norms) + usage update ----
  {
    const int m = tid>>2, q = tid&3;
    const float* mr = mem + ((size_t)b*64 + m)*512;
    float d = 0.f, ss = 0.f;
    for (int i = q*128; i < q*128+128; i += 4) {
      const float4 mv = *(const float4*)&mr[i];
      d = fmaf(mv.x, wk_s[i  ], d); d = fmaf(mv.y, wk_s[i+1], d);
      d = fmaf(mv.z, wk_s[i+2], d); d = fmaf(mv.w, wk_s[i+3], d);
      ss = fmaf(mv.x,mv.x,ss); ss = fmaf(mv.y,mv.y,ss);
      ss = fmaf(mv.z,mv.z,ss); ss = fmaf(mv.w,mv.w,ss);
    }
    d  += __shfl_xor(d,1,64);  d  += __shfl_xor(d,2,64);
    ss += __shfl_xor(ss,1,64); ss += __shfl_xor(ss,2,64);
    if (q == 0) wcw_s[m] = d / ((sqrtf(ss)+EPSF)*(sc[23]+EPSF)) * sc[4];
  }
  if (tid < 64) {
    const float uo = usage_s[tid];
    const float wwp = wwg[b*64+tid];
    float u = uo + (1.f-uo)*wwp;
    #pragma unroll
    for (int r=0;r<4;r++) u *= (1.f - sc[5+r]*rwp_s[r][tid]);
    usage_s[tid] = u; usg[b*64+tid] = u;
  }
  __syncthreads();
  // ---- phase 3: softmax(wcw), eps-adjusted usage ----
  if (tid < 64) {
    const float v = wcw_s[tid];
    const float mx = wredMax(v);
    const float e = __expf(v-mx);
    const float s2 = wredSum(e);
    wcw_s[tid] = e/s2;
    u_s[tid] = EPSF + (1.f-EPSF)*usage_s[tid];
  }
  __syncthreads();
  // ---- allocation: stable rank + cumprod ----
  if (tid < 64) {
    const float u = u_s[tid]; int rk2 = 0;
    for (int j=0;j<64;j++){ const float uj = u_s[j]; rk2 += (uj<u) || (uj==u && j<tid); }
    rank_s[tid] = rk2; sorted_s[rk2] = u;
  }
  __syncthreads();
  if (tid == 0) { float run = 1.f; for (int p2=0;p2<64;p2++){ excl_s[p2]=run; run*=sorted_s[p2]; } }
  __syncthreads();
  if (tid < 64) {
    const float al = (1.f - u_s[tid]) * excl_s[rank_s[tid]];
    const float wwv = sc[10]*(sc[9]*al + (1.f-sc[9])*wcw_s[tid]);
    ww_s[tid] = wwv; wwg[b*64+tid] = wwv;
    const float s3 = wredSum(wwv);
    if (tid==0) sc[28] = s3;
  }
  __syncthreads();
  // ---- phase 4: memory write + new norms ----
  {
    const int m = tid>>2, q = tid&3;
    const float wwm = ww_s[m];
    float* mr = mem + ((size_t)b*64 + m)*512;
    float ss = 0.f;
    for (int i = q*128; i < q*128+128; i += 4) {
      float4 mv = *(const float4*)&mr[i];
      mv.x = mv.x*(1.f - wwm*er_s[i  ]) + wwm*wv_s[i  ];
      mv.y = mv.y*(1.f - wwm*er_s[i+1]) + wwm*wv_s[i+1];
      mv.z = mv.z*(1.f - wwm*er_s[i+2]) + wwm*wv_s[i+2];
      mv.w = mv.w*(1.f - wwm*er_s[i+3]) + wwm*wv_s[i+3];
      *(float4*)&mr[i] = mv;
      ss += mv.x*mv.x + mv.y*mv.y + mv.z*mv.z + mv.w*mv.w;
    }
    ss += __shfl_xor(ss,1,64); ss += __shfl_xor(ss,2,64);
    if (q==0) mn_s[m] = sqrtf(ss);
  }
  __syncthreads();
  // ---- phase 5: link + precedence (uses OLD prec_s) ----
  {
    float* lrow = link + (size_t)b*4096;
    for (int e = tid; e < 4096; e += 256) {
      const int i2 = e>>6, j2 = e&63;
      const float ln2 = (i2==j2) ? 0.f
                 : ((1.f - ww_s[i2] - ww_s[j2])*lrow[e] + ww_s[i2]*prec_s[j2]);
      link_s[i2][j2] = ln2;
      lrow[e] = ln2;
    }
  }
  if (tid < 64) prec[b*64+tid] = (1.f - sc[28])*prec_s[tid] + ww_s[tid];
  __syncthreads();
  // ---- phase 6: cw (wave r = head r, lane = slot) ----
  const int r6 = tid>>6, m6 = tid&63;
  {
    const float* mr = mem + ((size_t)b*64 + m6)*512;
    const float* rkr = rk_s[r6];
    float d = 0.f;
    for (int i=0;i<512;i+=4){
      const float4 mv = *(const float4*)&mr[i];
      d = fmaf(mv.x, rkr[i  ], d); d = fmaf(mv.y, rkr[i+1], d);
      d = fmaf(mv.z, rkr[i+2], d); d = fmaf(mv.w, rkr[i+3], d);
    }
    const float cv = d / ((mn_s[m6]+EPSF)*(sc[24+r6]+EPSF)) * sc[r6];
    const float mx = wredMax(cv);
    const float e = __expf(cv-mx);
    const float s2 = wredSum(e);
    cw_s[r6][m6] = e/s2;
  }
  __syncthreads();
  // ---- phase 7: fwd/bwd + read weights ----
  {
    float fw = 0.f, bw = 0.f;
    #pragma unroll 8
    for (int m3=0;m3<64;m3++){
      const float rp = rwp_s[r6][m3];
      fw = fmaf(link_s[m6][m3], rp, fw);
      bw = fmaf(link_s[m3][m6], rp, bw);
    }
    const float rn = sc[11+3*r6]*bw + sc[12+3*r6]*fw + sc[13+3*r6]*cw_s[r6][m6];
    rwn_s[r6][m6] = rn;
    rwg[b*256 + r6*64 + m6] = rn;
  }
  __syncthreads();
  // ---- phase 8: read vectors rv -> full (decoder only) ----
  if (full != nullptr) {
    const int r8 = tid>>6, w0 = (tid&63)*8;
    float a[8];
    #pragma unroll
    for (int j=0;j<8;j++) a[j]=0.f;
    for (int m3=0;m3<64;m3++){
      const float rv_ = rwn_s[r8][m3];
      const float* mr = mem + ((size_t)b*64+m3)*512 + w0;
      const float4 p0 = *(const float4*)&mr[0];
      const float4 p1 = *(const float4*)&mr[4];
      a[0]=fmaf(rv_,p0.x,a[0]); a[1]=fmaf(rv_,p0.y,a[1]);
      a[2]=fmaf(rv_,p0.z,a[2]); a[3]=fmaf(rv_,p0.w,a[3]);
      a[4]=fmaf(rv_,p1.x,a[4]); a[5]=fmaf(rv_,p1.y,a[5]);
      a[6]=fmaf(rv_,p1.z,a[6]); a[7]=fmaf(rv_,p1.w,a[7]);
    }
    u16* dst = full + ((size_t)t*32 + b)*2560 + 512 + r8*512 + w0;
    ushort4 s0, s1;
    s0.x=f2b(a[0]); s0.y=f2b(a[1]); s0.z=f2b(a[2]); s0.w=f2b(a[3]);
    s1.x=f2b(a[4]); s1.y=f2b(a[5]); s1.z=f2b(a[6]); s1.w=f2b(a[7]);
    *(ushort4*)dst = s0;
    *(ushort4*)(dst+4) = s1;
  }
}

// y = full @ Wo.T + bo   (2048 x 512, K=2560). grid=1024 (64 row-tiles x 16 col-tiles)
__global__ __launch_bounds__(256) void k_y(
    const u16* __restrict__ full,
    const float* __restrict__ Wo, const float* __restrict__ bo,
    u16* __restrict__ y)
{
  __shared__ __align__(16) float As[32][136];
  const int tid = threadIdx.x;
  const int rb = blockIdx.x >> 4, cb = blockIdx.x & 15;
  const int c = tid & 31, col = cb*32 + c;
  const int b0 = (tid>>5)*4;
  float acc0=0.f,acc1=0.f,acc2=0.f,acc3=0.f;
  for (int chunk = 0; chunk < 20; ++chunk) {
    const int k0 = chunk*128;
    for (int i = tid; i < 1024; i += 256) {
      const int r = i>>5, kk = (i&31)*4;
      const float4 v = b4f(*(const ushort4*)&full[(size_t)(rb*32+r)*2560 + k0 + kk]);
      *(float4*)&As[r][kk] = v;
    }
    __syncthreads();
    const float* Wr = Wo + (size_t)col*2560 + k0;
    #pragma unroll 8
    for (int kk = 0; kk < 128; kk += 4) {
      const float4 w4 = *(const float4*)(Wr + kk);
      const float4 a0 = *(const float4*)&As[b0+0][kk];
      const float4 a1 = *(const float4*)&As[b0+1][kk];
      const float4 a2 = *(const float4*)&As[b0+2][kk];
      const float4 a3 = *(const float4*)&As[b0+3][kk];
      acc0 = fmaf(a0.x,w4.x,fmaf(a0.y,w4.y,fmaf(a0.z,w4.z,fmaf(a0.w,w4.w,acc0))));
      acc1 = fmaf(a1.x,w4.x,fmaf(a1.y,w4.y,fmaf(a1.z,w4.z,fmaf(a1.w,w4.w,acc1))));
      acc2 = fmaf(a2.x,w4.x,fmaf(a2.y,w4.y,fmaf(a2.z,w4.z,fmaf(a2.w,w4.w,acc2))));
      acc3 = fmaf(a3.x,w4.x,fmaf(a3.y,w4.y,fmaf(a3.z,w4.z,fmaf(a3.w,w4.w,acc3))));
    }
    __syncthreads();
  }
  const float bias = bo[col];
  y[(size_t)(rb*32+b0+0)*512+col] = f2b(acc0+bias);
  y[(size_t)(rb*32+b0+1)*512+col] = f2b(acc1+bias);
  y[(size_t)(rb*32+b0+2)*512+col] = f2b(acc2+bias);
  y[(size_t)(rb*32+b0+3)*512+col] = f2b(acc3+bias);
}

// logits: out[b,v,t] = sum_d y[(t,b),d]*fcW[v,d] + fcb[v]. grid = 32*157.
__global__ __launch_bounds__(256) void k_logits(
    const u16* __restrict__ y,
    const float* __restrict__ fcW, const float* __restrict__ fcb,
    float* __restrict__ outp)
{
  __shared__ __align__(16) float As[64][68];
  const int tid = threadIdx.x;
  const int bb = blockIdx.x / 157, vt = blockIdx.x % 157;
  const int tl = tid & 15, vl = tid >> 4;
  const int t0 = tl*4;
  const int vbase = vt*64 + vl*4;
  float acc[4][4];
  #pragma unroll
  for (int i=0;i<4;i++)
    #pragma unroll
    for (int j=0;j<4;j++) acc[i][j]=0.f;
  for (int chunk = 0; chunk < 8; ++chunk) {
    const int k0 = chunk*64;
    for (int i = tid; i < 1024; i += 256) {
      const int tt = i>>4, kk = (i&15)*4;
      const float4 v = b4f(*(const ushort4*)&y[((size_t)tt*32 + bb)*512 + k0 + kk]);
      *(float4*)&As[tt][kk] = v;
    }
    __syncthreads();
    for (int kk = 0; kk < 64; kk += 4) {
      const float4 a0 = *(const float4*)&As[t0+0][kk];
      const float4 a1 = *(const float4*)&As[t0+1][kk];
      const float4 a2 = *(const float4*)&As[t0+2][kk];
      const float4 a3 = *(const float4*)&As[t0+3][kk];
      #pragma unroll
      for (int vj = 0; vj < 4; ++vj) {
        const int v = vbase + vj;
        const int vc = v < VV ? v : VV-1;
        const float4 w4 = *(const float4*)(fcW + (size_t)vc*512 + k0 + kk);
        acc[vj][0] = fmaf(a0.x,w4.x,fmaf(a0.y,w4.y,fmaf(a0.z,w4.z,fmaf(a0.w,w4.w,acc[vj][0]))));
        acc[vj][1] = fmaf(a1.x,w4.x,fmaf(a1.y,w4.y,fmaf(a1.z,w4.z,fmaf(a1.w,w4.w,acc[vj][1]))));
        acc[vj][2] = fmaf(a2.x,w4.x,fmaf(a2.y,w4.y,fmaf(a2.z,w4.z,fmaf(a2.w,w4.w,acc[vj][2]))));
        acc[vj][3] = fmaf(a3.x,w4.x,fmaf(a3.y,w4.y,fmaf(a3.z,w4.z,fmaf(a3.w,w4.w,acc[vj][3]))));
      }
    }
    __syncthreads();
  }
  #pragma unroll
  for (int vj = 0; vj < 4; ++vj) {
    const int v = vbase + vj;
    if (v < VV) {
      const float bias = fcb[v];
      float4 st;
      st.x = acc[vj][0]+bias;
      st.y = acc[vj][1]+bias;
      st.z = acc[vj][2]+bias;
      st.w = acc[vj][3]+bias;
      *(float4*)&outp[(size_t)bb*640000 + (size_t)v*64 + t0] = st;
    }
  }
}

// ---- workspace layout ----
// f32 region (float indices):
#define O_H0A 0
#define O_H0B 16384
#define O_H1A 32768
#define O_H1B 49152
#define O_C0  65536
#define O_C1  81920
#define O_MEM 98304
#define O_LINK  1146880
#define O_PREC  1277952
#define O_RW    1280000
#define O_WW    1288192
#define O_USAGE 1290240
#define STATE_FLOATS 1292288
#define O_XI   1292288
#define O_OUT  1407712
#define F32_END 1424096
// u16 regions (byte offsets):
#define FULL_BYTE_OFF 5696384ull   // F32_END*4
#define Y_BYTE_OFF    16182144ull  // FULL + 64*32*2560*2
#define WS_NEED       18279296ull  // Y + 2048*512*2

extern "C" void kernel_launch(void* const* d_in, const int* in_sizes, int n_in,
                              void* d_out, int out_size, void* d_ws, size_t ws_size,
                              hipStream_t stream) {
  (void)in_sizes; (void)n_in; (void)out_size;
  if (ws_size < WS_NEED) return;   // diagnostic: zero output => ws too small
  typedef const float* cf;
  cf emb_src = (cf)d_in[0], emb_tgt = (cf)d_in[1];
  cf eW[12], dWt[12];
  for (int i=0;i<12;i++){ eW[i]=(cf)d_in[2+i]; dWt[i]=(cf)d_in[14+i]; }
  cf fcW = (cf)d_in[26], fcb = (cf)d_in[27];
  const int* inp = (const int*)d_in[28];
  const int* tgt = (const int*)d_in[29];
  float* outp = (float*)d_out;
  float* w = (float*)d_ws;

  float* h0buf[2] = { w+O_H0A, w+O_H0B };
  float* h1buf[2] = { w+O_H1A, w+O_H1B };
  float* c0 = w+O_C0;  float* c1 = w+O_C1;
  float* memb = w+O_MEM;
  float* linkb = w+O_LINK; float* precb = w+O_PREC;
  float* rwb = w+O_RW;     float* wwb = w+O_WW;   float* usageb = w+O_USAGE;
  float* xib = w+O_XI;     float* outb = w+O_OUT;
  u16* fullb = (u16*)((char*)d_ws + FULL_BYTE_OFF);
  u16* yb    = (u16*)((char*)d_ws + Y_BYTE_OFF);

  // zero all recurrent state every call (deterministic across graph replays)
  hipMemsetAsync(w, 0, (size_t)STATE_FLOATS*4, stream);

  // ---- encoder ----
  int pp = 0;
  for (int t = 0; t < TT; ++t) {
    k_lstm<<<64,256,0,stream>>>(eW[0], NNIN, eW[1], eW[2], eW[3],
                                emb_src, inp, t, nullptr,
                                h0buf[pp], h0buf[pp^1], c0, nullptr, nullptr);
    k_lstm<<<64,256,0,stream>>>(eW[4], 512, eW[5], eW[6], eW[7],
                                nullptr, nullptr, t, h0buf[pp^1],
                                h1buf[pp], h1buf[pp^1], c1, outb, nullptr);
    k_xi<<<113,256,0,stream>>>(outb, eW[8], eW[9], xib);
    k_mem<<<32,256,0,stream>>>(xib, memb, linkb, precb, rwb, wwb, usageb,
                               nullptr, t);
    pp ^= 1;
  }

  // reset h/c for decoder (memory state carries over)
  hipMemsetAsync(w, 0, (size_t)O_MEM*4, stream);

  // ---- decoder ----
  pp = 0;
  for (int t = 0; t < TT; ++t) {
    k_lstm<<<64,256,0,stream>>>(dWt[0], NNIN, dWt[1], dWt[2], dWt[3],
                                emb_tgt, tgt, t, nullptr,
                                h0buf[pp], h0buf[pp^1], c0, nullptr, nullptr);
    k_lstm<<<64,256,0,stream>>>(dWt[4], 512, dWt[5], dWt[6], dWt[7],
                                nullptr, nullptr, t, h0buf[pp^1],
                                h1buf[pp], h1buf[pp^1], c1, outb, fullb);
    k_xi<<<113,256,0,stream>>>(outb, dWt[8], dWt[9], xib);
    k_mem<<<32,256,0,stream>>>(xib, memb, linkb, precb, rwb, wwb, usageb,
                               fullb, t);
    pp ^= 1;
  }

  // ---- deferred output projections ----
  k_y<<<1024,256,0,stream>>>(fullb, dWt[10], dWt[11], yb);
  k_logits<<<32*157,256,0,stream>>>(yb, fcW, fcb, outp);
}

// Round 4
// 21957.405 us; speedup vs baseline: 1.3682x; 1.3682x over previous
//
#include <hip/hip_runtime.h>

#define BB   32
#define DD   512
#define RR   4
#define MM   64
#define VV   10000
#define TT   64
#define IFX  3607
#define NNIN 2560
#define EPSF 1e-6f

typedef unsigned short u16;

// bf16 helpers for INTERNAL scratch only (full/y buffers)
__device__ __forceinline__ float bf(u16 u){ return __uint_as_float(((unsigned)u)<<16); }
__device__ __forceinline__ float4 b4f(ushort4 u){
  float4 f; f.x = bf(u.x); f.y = bf(u.y); f.z = bf(u.z); f.w = bf(u.w); return f;
}
__device__ __forceinline__ u16 f2b(float f){
  unsigned u = __float_as_uint(f);
  u += 0x7fffu + ((u>>16)&1u);
  return (u16)(u>>16);
}
__device__ __forceinline__ float sigmf(float x){ return 1.f/(1.f+__expf(-x)); }
__device__ __forceinline__ float softplusf(float x){ return x > 20.f ? x : log1pf(__expf(x)); }
__device__ __forceinline__ float wredSum(float v){
  #pragma unroll
  for (int s=1;s<64;s<<=1) v += __shfl_xor(v,s,64);
  return v;
}
__device__ __forceinline__ float wredMax(float v){
  #pragma unroll
  for (int s=1;s<64;s<<=1) v = fmaxf(v, __shfl_xor(v,s,64));
  return v;
}

// Fused gates GEMM + LSTM cell update. LDS-staged, coalesced weight loads.
// Block: 32 gate-cols x 32 batches, grid=64, 256 thr.
__global__ __launch_bounds__(256) void k_lstm(
    const float* __restrict__ Wx, int wx_stride,
    const float* __restrict__ Wh,
    const float* __restrict__ bx, const float* __restrict__ bh,
    const float* __restrict__ emb, const int* __restrict__ seq, int t,
    const float* __restrict__ xf,
    const float* __restrict__ hprev, float* __restrict__ hcur,
    float* __restrict__ cst, float* __restrict__ outc, u16* __restrict__ full)
{
  __shared__ __align__(16) float As[32][132];
  __shared__ __align__(16) float Ws[32][132];
  __shared__ float gs[32*33];
  __shared__ int idxs[32];
  const int tid = threadIdx.x;
  const int c = tid & 31;                 // gate-col within block
  const int dblk = blockIdx.x * 8;
  const int gcol = ((c>>3)<<9) + dblk + (c&7);   // gate*512 + dblk + dl
  const int b0 = (tid >> 5) * 4;          // 8 groups x 4 batches
  float acc0=0.f, acc1=0.f, acc2=0.f, acc3=0.f;
  if (emb != nullptr && tid < 32) idxs[tid] = seq[tid*64 + t];
  __syncthreads();
  for (int chunk = 0; chunk < 8; ++chunk) {
    const int k0 = chunk * 128;
    const bool xp = (chunk < 4);
    // stage A tile: 32 batches x 128 K (coalesced f4)
    for (int i = tid; i < 1024; i += 256) {
      const int bb2 = i >> 5, f4i = (i & 31)*4;
      float4 v;
      if (xp) v = (emb != nullptr)
                  ? *(const float4*)&emb[(size_t)idxs[bb2]*512 + k0 + f4i]
                  : *(const float4*)&xf[bb2*512 + k0 + f4i];
      else    v = *(const float4*)&hprev[bb2*512 + (k0-512) + f4i];
      *(float4*)&As[bb2][f4i] = v;
    }
    // stage W tile: 32 gate-cols x 128 K (coalesced f4 along K)
    for (int i = tid; i < 1024; i += 256) {
      const int r = i >> 5, f4i = (i & 31)*4;
      const int gr = ((r>>3)<<9) + dblk + (r&7);
      const float4 v = xp ? *(const float4*)&Wx[(size_t)gr*wx_stride + k0 + f4i]
                          : *(const float4*)&Wh[(size_t)gr*512 + (k0-512) + f4i];
      *(float4*)&Ws[r][f4i] = v;
    }
    __syncthreads();
    #pragma unroll 8
    for (int kk = 0; kk < 128; kk += 4) {
      const float4 w4 = *(const float4*)&Ws[c][kk];
      const float4 a0 = *(const float4*)&As[b0+0][kk];
      const float4 a1 = *(const float4*)&As[b0+1][kk];
      const float4 a2 = *(const float4*)&As[b0+2][kk];
      const float4 a3 = *(const float4*)&As[b0+3][kk];
      acc0 = fmaf(a0.x,w4.x,fmaf(a0.y,w4.y,fmaf(a0.z,w4.z,fmaf(a0.w,w4.w,acc0))));
      acc1 = fmaf(a1.x,w4.x,fmaf(a1.y,w4.y,fmaf(a1.z,w4.z,fmaf(a1.w,w4.w,acc1))));
      acc2 = fmaf(a2.x,w4.x,fmaf(a2.y,w4.y,fmaf(a2.z,w4.z,fmaf(a2.w,w4.w,acc2))));
      acc3 = fmaf(a3.x,w4.x,fmaf(a3.y,w4.y,fmaf(a3.z,w4.z,fmaf(a3.w,w4.w,acc3))));
    }
    __syncthreads();
  }
  const float bias = bx[gcol] + bh[gcol];
  gs[c*33 + b0+0] = acc0 + bias;
  gs[c*33 + b0+1] = acc1 + bias;
  gs[c*33 + b0+2] = acc2 + bias;
  gs[c*33 + b0+3] = acc3 + bias;
  __syncthreads();
  {
    const int b2 = tid & 31, dl2 = tid >> 5;
    const float gi = gs[(0*8+dl2)*33 + b2];
    const float gf = gs[(1*8+dl2)*33 + b2];
    const float gg = gs[(2*8+dl2)*33 + b2];
    const float go = gs[(3*8+dl2)*33 + b2];
    const int d = dblk + dl2;
    const int cid = b2*512 + d;
    const float cv = sigmf(gf)*cst[cid] + sigmf(gi)*tanhf(gg);
    const float hv = sigmf(go)*tanhf(cv);
    cst[cid] = cv;
    hcur[cid] = hv;
    if (outc != nullptr) {
      const float oc = fminf(fmaxf(hv,-20.f),20.f);
      outc[cid] = oc;
      if (full != nullptr) full[((size_t)t*32 + b2)*2560 + d] = f2b(oc);
    }
  }
}

// xi = out @ Wi.T + bi  (B x IFX). grid=113 (32 cols each), 256 thr. LDS-staged.
__global__ __launch_bounds__(256) void k_xi(
    const float* __restrict__ outc,
    const float* __restrict__ Wi, const float* __restrict__ bi,
    float* __restrict__ xi)
{
  __shared__ __align__(16) float As[32][132];
  __shared__ __align__(16) float Ws[32][132];
  const int tid = threadIdx.x;
  const int c = tid & 31;
  const int col = blockIdx.x*32 + c;
  const int b0 = (tid>>5)*4;
  float acc0=0.f,acc1=0.f,acc2=0.f,acc3=0.f;
  for (int chunk = 0; chunk < 4; ++chunk) {
    const int k0 = chunk*128;
    for (int i = tid; i < 1024; i += 256) {
      const int bb2 = i>>5, f4i = (i&31)*4;
      *(float4*)&As[bb2][f4i] = *(const float4*)&outc[bb2*512 + k0 + f4i];
    }
    for (int i = tid; i < 1024; i += 256) {
      const int r = i>>5, f4i = (i&31)*4;
      int cr = blockIdx.x*32 + r; cr = cr < IFX ? cr : IFX-1;
      *(float4*)&Ws[r][f4i] = *(const float4*)&Wi[(size_t)cr*512 + k0 + f4i];
    }
    __syncthreads();
    #pragma unroll 8
    for (int kk = 0; kk < 128; kk += 4) {
      const float4 w4 = *(const float4*)&Ws[c][kk];
      const float4 a0 = *(const float4*)&As[b0+0][kk];
      const float4 a1 = *(const float4*)&As[b0+1][kk];
      const float4 a2 = *(const float4*)&As[b0+2][kk];
      const float4 a3 = *(const float4*)&As[b0+3][kk];
      acc0 = fmaf(a0.x,w4.x,fmaf(a0.y,w4.y,fmaf(a0.z,w4.z,fmaf(a0.w,w4.w,acc0))));
      acc1 = fmaf(a1.x,w4.x,fmaf(a1.y,w4.y,fmaf(a1.z,w4.z,fmaf(a1.w,w4.w,acc1))));
      acc2 = fmaf(a2.x,w4.x,fmaf(a2.y,w4.y,fmaf(a2.z,w4.z,fmaf(a2.w,w4.w,acc2))));
      acc3 = fmaf(a3.x,w4.x,fmaf(a3.y,w4.y,fmaf(a3.z,w4.z,fmaf(a3.w,w4.w,acc3))));
    }
    __syncthreads();
  }
  if (col < IFX) {
    const float bias = bi[col];
    xi[(size_t)(b0+0)*IFX + col] = acc0 + bias;
    xi[(size_t)(b0+1)*IFX + col] = acc1 + bias;
    xi[(size_t)(b0+2)*IFX + col] = acc2 + bias;
    xi[(size_t)(b0+3)*IFX + col] = acc3 + bias;
  }
}

// DNC memory step, one block per batch. 256 thr. Norms recomputed from mem.
__global__ __launch_bounds__(256) void k_mem(
    const float* __restrict__ xi,
    float* __restrict__ mem,
    float* __restrict__ link, float* __restrict__ prec,
    float* __restrict__ rwg, float* __restrict__ wwg, float* __restrict__ usg,
    u16* __restrict__ full, int t)
{
  const int b = blockIdx.x, tid = threadIdx.x;
  const float* xb = xi + (size_t)b*IFX;
  __shared__ __align__(16) float rk_s[4][512];
  __shared__ __align__(16) float wk_s[512];
  __shared__ __align__(16) float er_s[512];
  __shared__ __align__(16) float wv_s[512];
  __shared__ float rwp_s[4][64];
  __shared__ float prec_s[64], usage_s[64], wcw_s[64], u_s[64], ww_s[64];
  __shared__ float sorted_s[64], excl_s[64];
  __shared__ int rank_s[64];
  __shared__ float cw_s[4][64], rwn_s[4][64];
  __shared__ float link_s[64][65];
  __shared__ float mn_s[64];
  __shared__ float sc[40];
  // sc: [0..3] rs, [4] ws, [5..8] fg, [9] ag, [10] wg, [11..22] modes, [23] |wk|, [24..27] |rk_r|, [28] sum(ww)

  // ---- phase 0: parse xi (activations), load prev state ----
  for (int i = tid; i < 2048; i += 256) rk_s[i>>9][i&511] = tanhf(xb[i]);
  for (int i = tid; i < 512; i += 256) {
    wk_s[i] = tanhf(xb[2052+i]);
    er_s[i] = sigmf(xb[2565+i]);
    wv_s[i] = tanhf(xb[3077+i]);
  }
  rwp_s[tid>>6][tid&63] = rwg[b*256 + tid];
  if (tid < 64) { prec_s[tid] = prec[b*64+tid]; usage_s[tid] = usg[b*64+tid]; }
  if (tid == 0) {
    for (int r=0;r<4;r++) sc[r] = softplusf(xb[2048+r]);
    sc[4] = softplusf(xb[2564]);
    for (int r=0;r<4;r++) sc[5+r] = sigmf(xb[3589+r]);
    sc[9]  = sigmf(xb[3593]);
    sc[10] = sigmf(xb[3594]);
    for (int r=0;r<4;r++) {
      const float a0=xb[3595+3*r], a1=xb[3596+3*r], a2=xb[3597+3*r];
      const float mx=fmaxf(a0,fmaxf(a1,a2));
      const float e0=__expf(a0-mx), e1=__expf(a1-mx), e2=__expf(a2-mx);
      const float s=e0+e1+e2;
      sc[11+3*r]=e0/s; sc[12+3*r]=e1/s; sc[13+3*r]=e2/s;
    }
  }
  __syncthreads();
  // ---- norms of rk (wave r) and wk (wave 0) ----
  {
    const int wid = tid>>6, ln = tid&63;
    float p = 0.f;
    for (int i = ln; i < 512; i += 64) { const float v = rk_s[wid][i]; p = fmaf(v,v,p); }
    p = wredSum(p);
    if (ln == 0) sc[24+wid] = sqrtf(p);
    if (wid == 0) {
      float q2 = 0.f;
      for (int i = ln; i < 512; i += 64) { const float v = wk_s[i]; q2 = fmaf(v,v,q2); }
      q2 = wredSum(q2);
      if (ln == 0) sc[23] = sqrtf(q2);
    }
  }
  __syncthreads();
  // ---- phase 2: wcw raw cosine (old mem, fresh norms) + usage update ----
  {
    const int m = tid>>2, q = tid&3;
    const float* mr = mem + ((size_t)b*64 + m)*512;
    float d = 0.f, ss = 0.f;
    for (int i = q*128; i < q*128+128; i += 4) {
      const float4 mv = *(const float4*)&mr[i];
      d = fmaf(mv.x, wk_s[i  ], d); d = fmaf(mv.y, wk_s[i+1], d);
      d = fmaf(mv.z, wk_s[i+2], d); d = fmaf(mv.w, wk_s[i+3], d);
      ss = fmaf(mv.x,mv.x,ss); ss = fmaf(mv.y,mv.y,ss);
      ss = fmaf(mv.z,mv.z,ss); ss = fmaf(mv.w,mv.w,ss);
    }
    d  += __shfl_xor(d,1,64);  d  += __shfl_xor(d,2,64);
    ss += __shfl_xor(ss,1,64); ss += __shfl_xor(ss,2,64);
    if (q == 0) wcw_s[m] = d / ((sqrtf(ss)+EPSF)*(sc[23]+EPSF)) * sc[4];
  }
  if (tid < 64) {
    const float uo = usage_s[tid];
    const float wwp = wwg[b*64+tid];
    float u = uo + (1.f-uo)*wwp;
    #pragma unroll
    for (int r=0;r<4;r++) u *= (1.f - sc[5+r]*rwp_s[r][tid]);
    usage_s[tid] = u; usg[b*64+tid] = u;
  }
  __syncthreads();
  // ---- phase 3: softmax(wcw), eps-adjusted usage ----
  if (tid < 64) {
    const float v = wcw_s[tid];
    const float mx = wredMax(v);
    const float e = __expf(v-mx);
    const float s2 = wredSum(e);
    wcw_s[tid] = e/s2;
    u_s[tid] = EPSF + (1.f-EPSF)*usage_s[tid];
  }
  __syncthreads();
  // ---- allocation: stable rank + cumprod ----
  if (tid < 64) {
    const float u = u_s[tid]; int rk2 = 0;
    for (int j=0;j<64;j++){ const float uj = u_s[j]; rk2 += (uj<u) || (uj==u && j<tid); }
    rank_s[tid] = rk2; sorted_s[rk2] = u;
  }
  __syncthreads();
  if (tid == 0) { float run = 1.f; for (int p2=0;p2<64;p2++){ excl_s[p2]=run; run*=sorted_s[p2]; } }
  __syncthreads();
  if (tid < 64) {
    const float al = (1.f - u_s[tid]) * excl_s[rank_s[tid]];
    const float wwv = sc[10]*(sc[9]*al + (1.f-sc[9])*wcw_s[tid]);
    ww_s[tid] = wwv; wwg[b*64+tid] = wwv;
    const float s3 = wredSum(wwv);
    if (tid==0) sc[28] = s3;
  }
  __syncthreads();
  // ---- phase 4: memory write + new norms ----
  {
    const int m = tid>>2, q = tid&3;
    const float wwm = ww_s[m];
    float* mr = mem + ((size_t)b*64 + m)*512;
    float ss = 0.f;
    for (int i = q*128; i < q*128+128; i += 4) {
      float4 mv = *(const float4*)&mr[i];
      mv.x = mv.x*(1.f - wwm*er_s[i  ]) + wwm*wv_s[i  ];
      mv.y = mv.y*(1.f - wwm*er_s[i+1]) + wwm*wv_s[i+1];
      mv.z = mv.z*(1.f - wwm*er_s[i+2]) + wwm*wv_s[i+2];
      mv.w = mv.w*(1.f - wwm*er_s[i+3]) + wwm*wv_s[i+3];
      *(float4*)&mr[i] = mv;
      ss += mv.x*mv.x + mv.y*mv.y + mv.z*mv.z + mv.w*mv.w;
    }
    ss += __shfl_xor(ss,1,64); ss += __shfl_xor(ss,2,64);
    if (q==0) mn_s[m] = sqrtf(ss);
  }
  __syncthreads();
  // ---- phase 5: link + precedence (uses OLD prec_s) ----
  {
    float* lrow = link + (size_t)b*4096;
    for (int e = tid; e < 4096; e += 256) {
      const int i2 = e>>6, j2 = e&63;
      const float ln2 = (i2==j2) ? 0.f
                 : ((1.f - ww_s[i2] - ww_s[j2])*lrow[e] + ww_s[i2]*prec_s[j2]);
      link_s[i2][j2] = ln2;
      lrow[e] = ln2;
    }
  }
  if (tid < 64) prec[b*64+tid] = (1.f - sc[28])*prec_s[tid] + ww_s[tid];
  __syncthreads();
  // ---- phase 6: cw (wave r = head r, lane = slot) ----
  const int r6 = tid>>6, m6 = tid&63;
  {
    const float* mr = mem + ((size_t)b*64 + m6)*512;
    const float* rkr = rk_s[r6];
    float d = 0.f;
    for (int i=0;i<512;i+=4){
      const float4 mv = *(const float4*)&mr[i];
      d = fmaf(mv.x, rkr[i  ], d); d = fmaf(mv.y, rkr[i+1], d);
      d = fmaf(mv.z, rkr[i+2], d); d = fmaf(mv.w, rkr[i+3], d);
    }
    const float cv = d / ((mn_s[m6]+EPSF)*(sc[24+r6]+EPSF)) * sc[r6];
    const float mx = wredMax(cv);
    const float e = __expf(cv-mx);
    const float s2 = wredSum(e);
    cw_s[r6][m6] = e/s2;
  }
  __syncthreads();
  // ---- phase 7: fwd/bwd + read weights ----
  {
    float fw = 0.f, bw = 0.f;
    #pragma unroll 8
    for (int m3=0;m3<64;m3++){
      const float rp = rwp_s[r6][m3];
      fw = fmaf(link_s[m6][m3], rp, fw);
      bw = fmaf(link_s[m3][m6], rp, bw);
    }
    const float rn = sc[11+3*r6]*bw + sc[12+3*r6]*fw + sc[13+3*r6]*cw_s[r6][m6];
    rwn_s[r6][m6] = rn;
    rwg[b*256 + r6*64 + m6] = rn;
  }
  __syncthreads();
  // ---- phase 8: read vectors rv -> full (decoder only) ----
  if (full != nullptr) {
    const int r8 = tid>>6, w0 = (tid&63)*8;
    float a[8];
    #pragma unroll
    for (int j=0;j<8;j++) a[j]=0.f;
    for (int m3=0;m3<64;m3++){
      const float rv_ = rwn_s[r8][m3];
      const float* mr = mem + ((size_t)b*64+m3)*512 + w0;
      const float4 p0 = *(const float4*)&mr[0];
      const float4 p1 = *(const float4*)&mr[4];
      a[0]=fmaf(rv_,p0.x,a[0]); a[1]=fmaf(rv_,p0.y,a[1]);
      a[2]=fmaf(rv_,p0.z,a[2]); a[3]=fmaf(rv_,p0.w,a[3]);
      a[4]=fmaf(rv_,p1.x,a[4]); a[5]=fmaf(rv_,p1.y,a[5]);
      a[6]=fmaf(rv_,p1.z,a[6]); a[7]=fmaf(rv_,p1.w,a[7]);
    }
    u16* dst = full + ((size_t)t*32 + b)*2560 + 512 + r8*512 + w0;
    ushort4 s0, s1;
    s0.x=f2b(a[0]); s0.y=f2b(a[1]); s0.z=f2b(a[2]); s0.w=f2b(a[3]);
    s1.x=f2b(a[4]); s1.y=f2b(a[5]); s1.z=f2b(a[6]); s1.w=f2b(a[7]);
    *(ushort4*)dst = s0;
    *(ushort4*)(dst+4) = s1;
  }
}

// y = full @ Wo.T + bo   (2048 x 512, K=2560). grid=1024 (64 row-tiles x 16 col-tiles)
__global__ __launch_bounds__(256) void k_y(
    const u16* __restrict__ full,
    const float* __restrict__ Wo, const float* __restrict__ bo,
    u16* __restrict__ y)
{
  __shared__ __align__(16) float As[32][136];
  const int tid = threadIdx.x;
  const int rb = blockIdx.x >> 4, cb = blockIdx.x & 15;
  const int c = tid & 31, col = cb*32 + c;
  const int b0 = (tid>>5)*4;
  float acc0=0.f,acc1=0.f,acc2=0.f,acc3=0.f;
  for (int chunk = 0; chunk < 20; ++chunk) {
    const int k0 = chunk*128;
    for (int i = tid; i < 1024; i += 256) {
      const int r = i>>5, kk = (i&31)*4;
      const float4 v = b4f(*(const ushort4*)&full[(size_t)(rb*32+r)*2560 + k0 + kk]);
      *(float4*)&As[r][kk] = v;
    }
    __syncthreads();
    const float* Wr = Wo + (size_t)col*2560 + k0;
    #pragma unroll 8
    for (int kk = 0; kk < 128; kk += 4) {
      const float4 w4 = *(const float4*)(Wr + kk);
      const float4 a0 = *(const float4*)&As[b0+0][kk];
      const float4 a1 = *(const float4*)&As[b0+1][kk];
      const float4 a2 = *(const float4*)&As[b0+2][kk];
      const float4 a3 = *(const float4*)&As[b0+3][kk];
      acc0 = fmaf(a0.x,w4.x,fmaf(a0.y,w4.y,fmaf(a0.z,w4.z,fmaf(a0.w,w4.w,acc0))));
      acc1 = fmaf(a1.x,w4.x,fmaf(a1.y,w4.y,fmaf(a1.z,w4.z,fmaf(a1.w,w4.w,acc1))));
      acc2 = fmaf(a2.x,w4.x,fmaf(a2.y,w4.y,fmaf(a2.z,w4.z,fmaf(a2.w,w4.w,acc2))));
      acc3 = fmaf(a3.x,w4.x,fmaf(a3.y,w4.y,fmaf(a3.z,w4.z,fmaf(a3.w,w4.w,acc3))));
    }
    __syncthreads();
  }
  const float bias = bo[col];
  y[(size_t)(rb*32+b0+0)*512+col] = f2b(acc0+bias);
  y[(size_t)(rb*32+b0+1)*512+col] = f2b(acc1+bias);
  y[(size_t)(rb*32+b0+2)*512+col] = f2b(acc2+bias);
  y[(size_t)(rb*32+b0+3)*512+col] = f2b(acc3+bias);
}

// logits: out[b,v,t] = sum_d y[(t,b),d]*fcW[v,d] + fcb[v]. grid = 32*157.
__global__ __launch_bounds__(256) void k_logits(
    const u16* __restrict__ y,
    const float* __restrict__ fcW, const float* __restrict__ fcb,
    float* __restrict__ outp)
{
  __shared__ __align__(16) float As[64][68];
  const int tid = threadIdx.x;
  const int bb = blockIdx.x / 157, vt = blockIdx.x % 157;
  const int tl = tid & 15, vl = tid >> 4;
  const int t0 = tl*4;
  const int vbase = vt*64 + vl*4;
  float acc[4][4];
  #pragma unroll
  for (int i=0;i<4;i++)
    #pragma unroll
    for (int j=0;j<4;j++) acc[i][j]=0.f;
  for (int chunk = 0; chunk < 8; ++chunk) {
    const int k0 = chunk*64;
    for (int i = tid; i < 1024; i += 256) {
      const int tt = i>>4, kk = (i&15)*4;
      const float4 v = b4f(*(const ushort4*)&y[((size_t)tt*32 + bb)*512 + k0 + kk]);
      *(float4*)&As[tt][kk] = v;
    }
    __syncthreads();
    for (int kk = 0; kk < 64; kk += 4) {
      const float4 a0 = *(const float4*)&As[t0+0][kk];
      const float4 a1 = *(const float4*)&As[t0+1][kk];
      const float4 a2 = *(const float4*)&As[t0+2][kk];
      const float4 a3 = *(const float4*)&As[t0+3][kk];
      #pragma unroll
      for (int vj = 0; vj < 4; ++vj) {
        const int v = vbase + vj;
        const int vc = v < VV ? v : VV-1;
        const float4 w4 = *(const float4*)(fcW + (size_t)vc*512 + k0 + kk);
        acc[vj][0] = fmaf(a0.x,w4.x,fmaf(a0.y,w4.y,fmaf(a0.z,w4.z,fmaf(a0.w,w4.w,acc[vj][0]))));
        acc[vj][1] = fmaf(a1.x,w4.x,fmaf(a1.y,w4.y,fmaf(a1.z,w4.z,fmaf(a1.w,w4.w,acc[vj][1]))));
        acc[vj][2] = fmaf(a2.x,w4.x,fmaf(a2.y,w4.y,fmaf(a2.z,w4.z,fmaf(a2.w,w4.w,acc[vj][2]))));
        acc[vj][3] = fmaf(a3.x,w4.x,fmaf(a3.y,w4.y,fmaf(a3.z,w4.z,fmaf(a3.w,w4.w,acc[vj][3]))));
      }
    }
    __syncthreads();
  }
  #pragma unroll
  for (int vj = 0; vj < 4; ++vj) {
    const int v = vbase + vj;
    if (v < VV) {
      const float bias = fcb[v];
      float4 st;
      st.x = acc[vj][0]+bias;
      st.y = acc[vj][1]+bias;
      st.z = acc[vj][2]+bias;
      st.w = acc[vj][3]+bias;
      *(float4*)&outp[(size_t)bb*640000 + (size_t)v*64 + t0] = st;
    }
  }
}

// ---- workspace layout ----
// f32 region (float indices):
#define O_H0A 0
#define O_H0B 16384
#define O_H1A 32768
#define O_H1B 49152
#define O_C0  65536
#define O_C1  81920
#define O_MEM 98304
#define O_LINK  1146880
#define O_PREC  1277952
#define O_RW    1280000
#define O_WW    1288192
#define O_USAGE 1290240
#define STATE_FLOATS 1292288
#define O_XI   1292288
#define O_OUT  1407712
#define F32_END 1424096
// u16 regions (byte offsets):
#define FULL_BYTE_OFF 5696384ull   // F32_END*4
#define Y_BYTE_OFF    16182144ull  // FULL + 64*32*2560*2
#define WS_NEED       18279296ull  // Y + 2048*512*2

extern "C" void kernel_launch(void* const* d_in, const int* in_sizes, int n_in,
                              void* d_out, int out_size, void* d_ws, size_t ws_size,
                              hipStream_t stream) {
  (void)in_sizes; (void)n_in; (void)out_size;
  if (ws_size < WS_NEED) return;   // diagnostic: zero output => ws too small
  typedef const float* cf;
  cf emb_src = (cf)d_in[0], emb_tgt = (cf)d_in[1];
  cf eW[12], dWt[12];
  for (int i=0;i<12;i++){ eW[i]=(cf)d_in[2+i]; dWt[i]=(cf)d_in[14+i]; }
  cf fcW = (cf)d_in[26], fcb = (cf)d_in[27];
  const int* inp = (const int*)d_in[28];
  const int* tgt = (const int*)d_in[29];
  float* outp = (float*)d_out;
  float* w = (float*)d_ws;

  float* h0buf[2] = { w+O_H0A, w+O_H0B };
  float* h1buf[2] = { w+O_H1A, w+O_H1B };
  float* c0 = w+O_C0;  float* c1 = w+O_C1;
  float* memb = w+O_MEM;
  float* linkb = w+O_LINK; float* precb = w+O_PREC;
  float* rwb = w+O_RW;     float* wwb = w+O_WW;   float* usageb = w+O_USAGE;
  float* xib = w+O_XI;     float* outb = w+O_OUT;
  u16* fullb = (u16*)((char*)d_ws + FULL_BYTE_OFF);
  u16* yb    = (u16*)((char*)d_ws + Y_BYTE_OFF);

  // zero all recurrent state every call (deterministic across graph replays)
  hipMemsetAsync(w, 0, (size_t)STATE_FLOATS*4, stream);

  // ---- encoder ----
  int pp = 0;
  for (int t = 0; t < TT; ++t) {
    k_lstm<<<64,256,0,stream>>>(eW[0], NNIN, eW[1], eW[2], eW[3],
                                emb_src, inp, t, nullptr,
                                h0buf[pp], h0buf[pp^1], c0, nullptr, nullptr);
    k_lstm<<<64,256,0,stream>>>(eW[4], 512, eW[5], eW[6], eW[7],
                                nullptr, nullptr, t, h0buf[pp^1],
                                h1buf[pp], h1buf[pp^1], c1, outb, nullptr);
    k_xi<<<113,256,0,stream>>>(outb, eW[8], eW[9], xib);
    k_mem<<<32,256,0,stream>>>(xib, memb, linkb, precb, rwb, wwb, usageb,
                               nullptr, t);
    pp ^= 1;
  }

  // reset h/c for decoder (memory state carries over)
  hipMemsetAsync(w, 0, (size_t)O_MEM*4, stream);

  // ---- decoder ----
  pp = 0;
  for (int t = 0; t < TT; ++t) {
    k_lstm<<<64,256,0,stream>>>(dWt[0], NNIN, dWt[1], dWt[2], dWt[3],
                                emb_tgt, tgt, t, nullptr,
                                h0buf[pp], h0buf[pp^1], c0, nullptr, nullptr);
    k_lstm<<<64,256,0,stream>>>(dWt[4], 512, dWt[5], dWt[6], dWt[7],
                                nullptr, nullptr, t, h0buf[pp^1],
                                h1buf[pp], h1buf[pp^1], c1, outb, fullb);
    k_xi<<<113,256,0,stream>>>(outb, dWt[8], dWt[9], xib);
    k_mem<<<32,256,0,stream>>>(xib, memb, linkb, precb, rwb, wwb, usageb,
                               fullb, t);
    pp ^= 1;
  }

  // ---- deferred output projections ----
  k_y<<<1024,256,0,stream>>>(fullb, dWt[10], dWt[11], yb);
  k_logits<<<32*157,256,0,stream>>>(yb, fcW, fcb, outp);
}